// Round 1
// baseline (284.112 us; speedup 1.0000x reference)
//
#include <hip/hip_runtime.h>
#include <hip/hip_bf16.h>

#define NROWS 8192
#define DEMB 256
#define CSPLIT 8
#define COLCHUNK (NROWS / CSPLIT)
#define MARGIN 0.2f

typedef __attribute__((ext_vector_type(4))) float f32x4;
typedef __attribute__((ext_vector_type(8))) short bf16x8;

static __device__ __forceinline__ unsigned short f2b(float f) {
    unsigned u = __builtin_bit_cast(unsigned, f);
    u += 0x7fffu + ((u >> 16) & 1u);           // RNE round to bf16
    return (unsigned short)(u >> 16);
}
static __device__ __forceinline__ float b2f(unsigned short b) {
    unsigned u = ((unsigned)b) << 16;
    return __builtin_bit_cast(float, u);
}

// K1: row-L2-normalize fp32 -> bf16. One wave per row.
__global__ __launch_bounds__(256) void k_norm(const float* __restrict__ x,
                                              unsigned short* __restrict__ xnb) {
    int row  = (blockIdx.x * blockDim.x + threadIdx.x) >> 6;
    int lane = threadIdx.x & 63;
    const float4* p = reinterpret_cast<const float4*>(x + (size_t)row * DEMB) + lane;
    float4 v = *p;
    float s = v.x * v.x + v.y * v.y + v.z * v.z + v.w * v.w;
#pragma unroll
    for (int m = 1; m < 64; m <<= 1) s += __shfl_xor(s, m);
    float inv = 1.0f / fmaxf(sqrtf(s), 1e-8f);
    ushort4 o;
    o.x = f2b(v.x * inv); o.y = f2b(v.y * inv);
    o.z = f2b(v.z * inv); o.w = f2b(v.w * inv);
    *(reinterpret_cast<ushort4*>(xnb + (size_t)row * DEMB) + lane) = o;
}

// K2: per-anchor max over negatives of dot(xn_a, xn_j), via 16x16x32 bf16 MFMA.
// Wave owns 16 anchor rows; block = 4 waves = 64 rows; blockIdx.y = column chunk.
// Writes partial max per (row, chunk).
__global__ __launch_bounds__(256) void k_maxneg(const unsigned short* __restrict__ xnb,
                                                const int* __restrict__ labels,
                                                float* __restrict__ pmax) {
    int wave = threadIdx.x >> 6;
    int lane = threadIdx.x & 63;
    int i0   = blockIdx.x * 64 + wave * 16;   // wave's 16 anchor rows
    int arow = lane & 15;                     // A-frag row within tile / B-frag col
    int kgrp = lane >> 4;                     // k-group 0..3 (8 elems each)

    // Hoist A fragments for all 8 k-slices (K=256 = 8 * 32)
    bf16x8 a[8];
    const unsigned short* aptr = xnb + (size_t)(i0 + arow) * DEMB + kgrp * 8;
#pragma unroll
    for (int kk = 0; kk < 8; ++kk)
        a[kk] = *reinterpret_cast<const bf16x8*>(aptr + kk * 32);

    // Labels of this lane's 4 C-rows (C layout: col=lane&15, row=(lane>>4)*4+reg)
    int rlab[4];
#pragma unroll
    for (int r = 0; r < 4; ++r) rlab[r] = labels[i0 + kgrp * 4 + r];

    float mx[4] = {-1e30f, -1e30f, -1e30f, -1e30f};

    int j0 = blockIdx.y * COLCHUNK;
    for (int jt = 0; jt < COLCHUNK; jt += 32) {
        int jA = j0 + jt, jB = j0 + jt + 16;
        const unsigned short* bpA = xnb + (size_t)(jA + arow) * DEMB + kgrp * 8;
        const unsigned short* bpB = xnb + (size_t)(jB + arow) * DEMB + kgrp * 8;
        int clabA = labels[jA + arow];
        int clabB = labels[jB + arow];
        f32x4 accA = {0.f, 0.f, 0.f, 0.f};
        f32x4 accB = {0.f, 0.f, 0.f, 0.f};
#pragma unroll
        for (int kk = 0; kk < 8; ++kk) {
            bf16x8 bA = *reinterpret_cast<const bf16x8*>(bpA + kk * 32);
            bf16x8 bB = *reinterpret_cast<const bf16x8*>(bpB + kk * 32);
            accA = __builtin_amdgcn_mfma_f32_16x16x32_bf16(a[kk], bA, accA, 0, 0, 0);
            accB = __builtin_amdgcn_mfma_f32_16x16x32_bf16(a[kk], bB, accB, 0, 0, 0);
        }
#pragma unroll
        for (int r = 0; r < 4; ++r) {
            if (rlab[r] != clabA) mx[r] = fmaxf(mx[r], accA[r]);
            if (rlab[r] != clabB) mx[r] = fmaxf(mx[r], accB[r]);
        }
    }

    // Row-max across the 16 column-slot lanes (masks 1,2,4,8 stay in group)
#pragma unroll
    for (int m = 1; m < 16; m <<= 1) {
#pragma unroll
        for (int r = 0; r < 4; ++r) mx[r] = fmaxf(mx[r], __shfl_xor(mx[r], m));
    }
    if (arow == 0) {
#pragma unroll
        for (int r = 0; r < 4; ++r)
            pmax[(size_t)(i0 + kgrp * 4 + r) * CSPLIT + blockIdx.y] = mx[r];
    }
}

// K3: reduce partial maxes -> dmin_neg, has_neg
__global__ __launch_bounds__(256) void k_dmin(const float* __restrict__ pmax,
                                              float* __restrict__ dmin,
                                              int* __restrict__ hasneg) {
    int i = blockIdx.x * 256 + threadIdx.x;
    float m = -1e30f;
#pragma unroll
    for (int c = 0; c < CSPLIT; ++c) m = fmaxf(m, pmax[(size_t)i * CSPLIT + c]);
    int hn = m > -1e29f;
    hasneg[i] = hn;
    dmin[i] = hn ? 1.0f - m : 1e9f;
}

// K4: pair losses. One wave per anchor a; scan p>a for same label; compute
// matched dots wave-parallel; lane 0 accumulates. Deterministic partials.
__global__ __launch_bounds__(256) void k_pairs(const unsigned short* __restrict__ xnb,
                                               const int* __restrict__ labels,
                                               const float* __restrict__ dmin,
                                               const int* __restrict__ hasneg,
                                               float* __restrict__ wloss,
                                               int* __restrict__ wcount) {
    int a    = (blockIdx.x * blockDim.x + threadIdx.x) >> 6;
    int lane = threadIdx.x & 63;
    float lsum = 0.f;
    int cnt = 0;
    if (hasneg[a]) {
        int la = labels[a];
        float da = dmin[a];
        float xa[4];
        {
            ushort4 av = *reinterpret_cast<const ushort4*>(xnb + (size_t)a * DEMB + lane * 4);
            xa[0] = b2f(av.x); xa[1] = b2f(av.y); xa[2] = b2f(av.z); xa[3] = b2f(av.w);
        }
        for (int p0 = a + 1; p0 < NROWS; p0 += 64) {
            int p = p0 + lane;
            bool match = (p < NROWS) && (labels[p] == la);
            unsigned long long mask = __ballot(match);
            while (mask) {
                int b = __builtin_ctzll(mask);
                mask &= mask - 1;
                int pp = p0 + b;
                ushort4 bv = *reinterpret_cast<const ushort4*>(xnb + (size_t)pp * DEMB + lane * 4);
                float part = xa[0] * b2f(bv.x) + xa[1] * b2f(bv.y)
                           + xa[2] * b2f(bv.z) + xa[3] * b2f(bv.w);
#pragma unroll
                for (int m = 1; m < 64; m <<= 1) part += __shfl_xor(part, m);
                if (lane == 0) {
                    float l = fmaxf(1.0f - part - da + MARGIN, 0.0f);
                    lsum += l;
                    cnt += 1;
                }
            }
        }
    }
    if (lane == 0) {
        wloss[a]  = lsum;
        wcount[a] = cnt;
    }
}

// K5: deterministic final reduce -> out[0]=loss, out[1]=count
__global__ __launch_bounds__(256) void k_final(const float* __restrict__ wloss,
                                               const int* __restrict__ wcount,
                                               float* __restrict__ out) {
    __shared__ float sl[256];
    __shared__ int   sc[256];
    float s = 0.f;
    int c = 0;
    for (int i = threadIdx.x; i < NROWS; i += 256) {
        s += wloss[i];
        c += wcount[i];
    }
    sl[threadIdx.x] = s; sc[threadIdx.x] = c;
    __syncthreads();
    for (int st = 128; st > 0; st >>= 1) {
        if (threadIdx.x < st) {
            sl[threadIdx.x] += sl[threadIdx.x + st];
            sc[threadIdx.x] += sc[threadIdx.x + st];
        }
        __syncthreads();
    }
    if (threadIdx.x == 0) {
        out[0] = (sc[0] > 0) ? sl[0] / (float)sc[0] : 0.0f;
        out[1] = (float)sc[0];
    }
}

extern "C" void kernel_launch(void* const* d_in, const int* in_sizes, int n_in,
                              void* d_out, int out_size, void* d_ws, size_t ws_size,
                              hipStream_t stream) {
    const float* emb   = (const float*)d_in[0];
    const int* labels  = (const int*)d_in[1];   // integer inputs arrive as int32
    float* out = (float*)d_out;

    char* ws = (char*)d_ws;
    unsigned short* xnb = (unsigned short*)ws;                          // 4 MB
    float* pmax   = (float*)(ws + (size_t)4 * 1024 * 1024);             // 256 KB
    float* dmin   = (float*)(ws + (size_t)4 * 1024 * 1024 + 262144);    // 32 KB
    int*   hasneg = (int*)  (ws + (size_t)4 * 1024 * 1024 + 262144 + 32768);
    float* wloss  = (float*)(ws + (size_t)4 * 1024 * 1024 + 262144 + 65536);
    int*   wcount = (int*)  (ws + (size_t)4 * 1024 * 1024 + 262144 + 65536 + 32768);

    k_norm<<<NROWS / 4, 256, 0, stream>>>(emb, xnb);
    dim3 g2(NROWS / 64, CSPLIT);
    k_maxneg<<<g2, 256, 0, stream>>>(xnb, labels, pmax);
    k_dmin<<<NROWS / 256, 256, 0, stream>>>(pmax, dmin, hasneg);
    k_pairs<<<NROWS / 4, 256, 0, stream>>>(xnb, labels, dmin, hasneg, wloss, wcount);
    k_final<<<1, 256, 0, stream>>>(wloss, wcount, out);
}

// Round 2
// 122.593 us; speedup vs baseline: 2.3175x; 2.3175x over previous
//
#include <hip/hip_runtime.h>
#include <hip/hip_bf16.h>

#define NROWS 8192
#define DEMB 256
#define MARGIN 0.2f
#define BM 128
#define BK 64

typedef __attribute__((ext_vector_type(4))) float f32x4;
typedef __attribute__((ext_vector_type(8))) short bf16x8;

static __device__ __forceinline__ unsigned short f2b(float f) {
    unsigned u = __builtin_bit_cast(unsigned, f);
    u += 0x7fffu + ((u >> 16) & 1u);           // RNE round to bf16
    return (unsigned short)(u >> 16);
}
static __device__ __forceinline__ float b2f(unsigned short b) {
    unsigned u = ((unsigned)b) << 16;
    return __builtin_bit_cast(float, u);
}
// order-preserving f32 -> u32 encode (max-compatible)
static __device__ __forceinline__ unsigned encf(float f) {
    unsigned u = __builtin_bit_cast(unsigned, f);
    return (u & 0x80000000u) ? ~u : (u | 0x80000000u);
}
static __device__ __forceinline__ float decf(unsigned e) {
    unsigned u = (e & 0x80000000u) ? (e ^ 0x80000000u) : ~e;
    return __builtin_bit_cast(float, u);
}
static __device__ __forceinline__ void gload16(const void* g, void* l) {
    __builtin_amdgcn_global_load_lds(
        (const __attribute__((address_space(1))) unsigned int*)g,
        (__attribute__((address_space(3))) unsigned int*)l, 16, 0, 0);
}

// K1: row-L2-normalize fp32 -> bf16. One wave per row.
__global__ __launch_bounds__(256) void k_norm(const float* __restrict__ x,
                                              unsigned short* __restrict__ xnb) {
    int row  = (blockIdx.x * blockDim.x + threadIdx.x) >> 6;
    int lane = threadIdx.x & 63;
    const float4* p = reinterpret_cast<const float4*>(x + (size_t)row * DEMB) + lane;
    float4 v = *p;
    float s = v.x * v.x + v.y * v.y + v.z * v.z + v.w * v.w;
#pragma unroll
    for (int m = 1; m < 64; m <<= 1) s += __shfl_xor(s, m);
    float inv = 1.0f / fmaxf(sqrtf(s), 1e-8f);
    ushort4 o;
    o.x = f2b(v.x * inv); o.y = f2b(v.y * inv);
    o.z = f2b(v.z * inv); o.w = f2b(v.w * inv);
    *(reinterpret_cast<ushort4*>(xnb + (size_t)row * DEMB) + lane) = o;
}

// K2: tiled MFMA "GEMM-max". 128x128 tile, BK=64, 4 waves each 64x64.
// LDS double-buffered via global_load_lds w16; XOR swizzle (row&7)<<4 on byte col.
// Epilogue: label-mask, row-max, deterministic atomicMax on encoded f32.
__global__ __launch_bounds__(256, 2) void k_maxneg(const unsigned short* __restrict__ xnb,
                                                   const int* __restrict__ labels,
                                                   unsigned* __restrict__ amax) {
    extern __shared__ char lds[];
    unsigned short* tile = (unsigned short*)lds;   // A0 @0, A1 @8192, B0 @16384, B1 @24576 (ushorts)

    int tid  = threadIdx.x;
    int wid  = tid >> 6, lane = tid & 63;
    int wr   = wid >> 1, wc = wid & 1;
    int arow = lane & 15, kgrp = lane >> 4;
    int sw   = (arow & 7) << 4;

    int i0 = blockIdx.x * BM;
    int j0 = blockIdx.y * BM;
    const unsigned short* Ag = xnb + (size_t)i0 * DEMB;
    const unsigned short* Bg = xnb + (size_t)j0 * DEMB;

    // per-lane ds_read byte offsets (swizzled)
    int c0 = (kgrp * 16) ^ sw;
    int c1 = (64 + kgrp * 16) ^ sw;
    int abase = (wr * 64 + arow) * 128;
    int bbase = (wc * 64 + arow) * 128;

    f32x4 acc[4][4] = {};

    // stage one K-slice of A and B into buffer `buf` (linear dest, pre-swizzled src)
    auto stage = [&](int buf, int k0) {
#pragma unroll
        for (int i = 0; i < 4; ++i) {
            int idx  = i * 256 + tid;            // 16B chunk index
            int row  = idx >> 3;                 // 8 chunks per 128B row
            int colb = (idx & 7) << 4;
            int scol = (colb ^ ((row & 7) << 4)) >> 1;  // element col in [0,64)
            const unsigned short* sa = Ag + (size_t)row * DEMB + k0 + scol;
            const unsigned short* sb = Bg + (size_t)row * DEMB + k0 + scol;
            // wave-uniform LDS base (ushort units); HW adds lane*16B
            unsigned short* da = tile + buf * 8192 + i * 2048 + wid * 512;
            unsigned short* db = tile + 16384 + buf * 8192 + i * 2048 + wid * 512;
            gload16(sa, da);
            gload16(sb, db);
        }
    };

    stage(0, 0);
#pragma unroll
    for (int ks = 0; ks < 4; ++ks) {
        __syncthreads();                          // buf[ks&1] ready (prev barrier drained vmcnt)
        if (ks < 3) stage((ks + 1) & 1, (ks + 1) * BK);  // prefetch overlaps compute
        const char* At = (const char*)(tile + (ks & 1) * 8192);
        const char* Bt = (const char*)(tile + 16384 + (ks & 1) * 8192);
        bf16x8 a[4][2], b[4][2];
#pragma unroll
        for (int m = 0; m < 4; ++m) {
            a[m][0] = *(const bf16x8*)(At + abase + m * 2048 + c0);
            a[m][1] = *(const bf16x8*)(At + abase + m * 2048 + c1);
            b[m][0] = *(const bf16x8*)(Bt + bbase + m * 2048 + c0);
            b[m][1] = *(const bf16x8*)(Bt + bbase + m * 2048 + c1);
        }
#pragma unroll
        for (int m = 0; m < 4; ++m)
#pragma unroll
            for (int n = 0; n < 4; ++n) {
                acc[m][n] = __builtin_amdgcn_mfma_f32_16x16x32_bf16(a[m][0], b[n][0], acc[m][n], 0, 0, 0);
                acc[m][n] = __builtin_amdgcn_mfma_f32_16x16x32_bf16(a[m][1], b[n][1], acc[m][n], 0, 0, 0);
            }
    }

    __syncthreads();                              // all tile reads done; reuse LDS for smax
    float* smax = (float*)tile;                   // [2][128]

    int clab[4];
#pragma unroll
    for (int n = 0; n < 4; ++n) clab[n] = labels[j0 + wc * 64 + n * 16 + arow];

#pragma unroll
    for (int m = 0; m < 4; ++m) {
#pragma unroll
        for (int r = 0; r < 4; ++r) {
            int rl = labels[i0 + wr * 64 + m * 16 + kgrp * 4 + r];
            float v = -1e30f;
#pragma unroll
            for (int n = 0; n < 4; ++n)
                if (clab[n] != rl) v = fmaxf(v, acc[m][n][r]);
#pragma unroll
            for (int msk = 1; msk < 16; msk <<= 1) v = fmaxf(v, __shfl_xor(v, msk));
            if (arow == 0) smax[wc * 128 + wr * 64 + m * 16 + kgrp * 4 + r] = v;
        }
    }
    __syncthreads();
    if (tid < 128) {
        float v = fmaxf(smax[tid], smax[128 + tid]);
        if (v > -1e29f) atomicMax(amax + i0 + tid, encf(v));
    }
}

// K3: decode amax -> dmin_neg, has_neg
__global__ __launch_bounds__(256) void k_dmin(const unsigned* __restrict__ amax,
                                              float* __restrict__ dmin,
                                              int* __restrict__ hasneg) {
    int i = blockIdx.x * 256 + threadIdx.x;
    unsigned e = amax[i];
    int hn = (e != 0u);
    hasneg[i] = hn;
    dmin[i] = hn ? 1.0f - decf(e) : 1e9f;
}

// K4: pair losses. Block caches all labels in LDS; one wave per anchor.
__global__ __launch_bounds__(256) void k_pairs(const unsigned short* __restrict__ xnb,
                                               const int* __restrict__ labels,
                                               const float* __restrict__ dmin,
                                               const int* __restrict__ hasneg,
                                               float* __restrict__ wloss,
                                               int* __restrict__ wcount) {
    __shared__ int slab[NROWS];                   // 32 KB
    for (int i = threadIdx.x; i < NROWS; i += 256) slab[i] = labels[i];
    __syncthreads();

    int a    = (blockIdx.x * blockDim.x + threadIdx.x) >> 6;
    int lane = threadIdx.x & 63;
    float lsum = 0.f;
    int cnt = 0;
    if (hasneg[a]) {
        int la = slab[a];
        float da = dmin[a];
        float xa[4];
        {
            ushort4 av = *reinterpret_cast<const ushort4*>(xnb + (size_t)a * DEMB + lane * 4);
            xa[0] = b2f(av.x); xa[1] = b2f(av.y); xa[2] = b2f(av.z); xa[3] = b2f(av.w);
        }
        for (int p0 = a + 1; p0 < NROWS; p0 += 64) {
            int p = p0 + lane;
            bool match = (p < NROWS) && (slab[p & (NROWS - 1)] == la);
            unsigned long long mask = __ballot(match);
            while (mask) {
                int b = __builtin_ctzll(mask);
                mask &= mask - 1;
                int pp = p0 + b;
                ushort4 bv = *reinterpret_cast<const ushort4*>(xnb + (size_t)pp * DEMB + lane * 4);
                float part = xa[0] * b2f(bv.x) + xa[1] * b2f(bv.y)
                           + xa[2] * b2f(bv.z) + xa[3] * b2f(bv.w);
#pragma unroll
                for (int m = 1; m < 64; m <<= 1) part += __shfl_xor(part, m);
                if (lane == 0) {
                    lsum += fmaxf(1.0f - part - da + MARGIN, 0.0f);
                    cnt += 1;
                }
            }
        }
    }
    if (lane == 0) {
        wloss[a]  = lsum;
        wcount[a] = cnt;
    }
}

// K5: deterministic final reduce -> out[0]=loss, out[1]=count
__global__ __launch_bounds__(256) void k_final(const float* __restrict__ wloss,
                                               const int* __restrict__ wcount,
                                               float* __restrict__ out) {
    __shared__ float sl[256];
    __shared__ int   sc[256];
    float s = 0.f;
    int c = 0;
    for (int i = threadIdx.x; i < NROWS; i += 256) {
        s += wloss[i];
        c += wcount[i];
    }
    sl[threadIdx.x] = s; sc[threadIdx.x] = c;
    __syncthreads();
    for (int st = 128; st > 0; st >>= 1) {
        if (threadIdx.x < st) {
            sl[threadIdx.x] += sl[threadIdx.x + st];
            sc[threadIdx.x] += sc[threadIdx.x + st];
        }
        __syncthreads();
    }
    if (threadIdx.x == 0) {
        out[0] = (sc[0] > 0) ? sl[0] / (float)sc[0] : 0.0f;
        out[1] = (float)sc[0];
    }
}

extern "C" void kernel_launch(void* const* d_in, const int* in_sizes, int n_in,
                              void* d_out, int out_size, void* d_ws, size_t ws_size,
                              hipStream_t stream) {
    const float* emb  = (const float*)d_in[0];
    const int* labels = (const int*)d_in[1];
    float* out = (float*)d_out;

    char* ws = (char*)d_ws;
    unsigned short* xnb = (unsigned short*)ws;                             // 4 MB
    unsigned* amax = (unsigned*)(ws + (size_t)4 * 1024 * 1024);            // 32 KB
    float* dmin    = (float*)   (ws + (size_t)4 * 1024 * 1024 + 32768);    // 32 KB
    int*   hasneg  = (int*)     (ws + (size_t)4 * 1024 * 1024 + 65536);    // 32 KB
    float* wloss   = (float*)   (ws + (size_t)4 * 1024 * 1024 + 98304);    // 32 KB
    int*   wcount  = (int*)     (ws + (size_t)4 * 1024 * 1024 + 131072);   // 32 KB

    k_norm<<<NROWS / 4, 256, 0, stream>>>(emb, xnb);
    hipMemsetAsync(amax, 0, NROWS * sizeof(unsigned), stream);
    dim3 g2(NROWS / BM, NROWS / BM);
    k_maxneg<<<g2, 256, 65536, stream>>>(xnb, labels, amax);
    k_dmin<<<NROWS / 256, 256, 0, stream>>>(amax, dmin, hasneg);
    k_pairs<<<NROWS / 4, 256, 0, stream>>>(xnb, labels, dmin, hasneg, wloss, wcount);
    k_final<<<1, 256, 0, stream>>>(wloss, wcount, out);
}

// Round 3
// 88.286 us; speedup vs baseline: 3.2181x; 1.3886x over previous
//
#include <hip/hip_runtime.h>
#include <hip/hip_bf16.h>

#define NROWS 8192
#define DEMB 256
#define MARGIN 0.2f
#define BM 128
#define BK 64
#define NT (NROWS / BM)          // 64 tile-rows
#define NBLK (NT * (NT + 1) / 2) // 2080 upper-tri blocks
#define NCLS 512
#define NCAP 96                  // max class size (mean 16, 96 is >15 sigma)

typedef __attribute__((ext_vector_type(4))) float f32x4;
typedef __attribute__((ext_vector_type(8))) short bf16x8;

static __device__ __forceinline__ unsigned short f2b(float f) {
    unsigned u = __builtin_bit_cast(unsigned, f);
    u += 0x7fffu + ((u >> 16) & 1u);           // RNE round to bf16
    return (unsigned short)(u >> 16);
}
static __device__ __forceinline__ float b2f(unsigned short b) {
    unsigned u = ((unsigned)b) << 16;
    return __builtin_bit_cast(float, u);
}
// order-preserving f32 -> u32 encode (max-compatible; finite inputs never encode to 0)
static __device__ __forceinline__ unsigned encf(float f) {
    unsigned u = __builtin_bit_cast(unsigned, f);
    return (u & 0x80000000u) ? ~u : (u | 0x80000000u);
}
static __device__ __forceinline__ float decf(unsigned e) {
    unsigned u = (e & 0x80000000u) ? (e ^ 0x80000000u) : ~e;
    return __builtin_bit_cast(float, u);
}
static __device__ __forceinline__ void gload16(const void* g, void* l) {
    __builtin_amdgcn_global_load_lds(
        (const __attribute__((address_space(1))) unsigned int*)g,
        (__attribute__((address_space(3))) unsigned int*)l, 16, 0, 0);
}

// K1: row-L2-normalize fp32 -> bf16. One wave per row.
__global__ __launch_bounds__(256) void k_norm(const float* __restrict__ x,
                                              unsigned short* __restrict__ xnb) {
    int row  = (blockIdx.x * blockDim.x + threadIdx.x) >> 6;
    int lane = threadIdx.x & 63;
    const float4* p = reinterpret_cast<const float4*>(x + (size_t)row * DEMB) + lane;
    float4 v = *p;
    float s = v.x * v.x + v.y * v.y + v.z * v.z + v.w * v.w;
#pragma unroll
    for (int m = 1; m < 64; m <<= 1) s += __shfl_xor(s, m);
    float inv = 1.0f / fmaxf(sqrtf(s), 1e-8f);
    ushort4 o;
    o.x = f2b(v.x * inv); o.y = f2b(v.y * inv);
    o.z = f2b(v.z * inv); o.w = f2b(v.w * inv);
    *(reinterpret_cast<ushort4*>(xnb + (size_t)row * DEMB) + lane) = o;
}

// K2: symmetric tiled MFMA "GEMM-max", upper-triangular block grid.
// Each block computes a 128x128 tile of the Gram matrix; epilogue extracts
// row-max (anchors = rows) AND col-max (anchors = cols, via symmetry),
// both label-masked, atomicMax'ed into amax (order-preserving encoding).
__global__ __launch_bounds__(256, 2) void k_maxneg(const unsigned short* __restrict__ xnb,
                                                   const int* __restrict__ labels,
                                                   unsigned* __restrict__ amax) {
    extern __shared__ char lds[];
    unsigned short* tile = (unsigned short*)lds;   // A0 @0, A1 @8192, B0 @16384, B1 @24576 (ushorts)
    __shared__ int slabR[128], slabC[128];

    int tid  = threadIdx.x;
    int wid  = tid >> 6, lane = tid & 63;
    int wr   = wid >> 1, wc = wid & 1;
    int arow = lane & 15, kgrp = lane >> 4;
    int sw   = (arow & 7) << 4;

    // triangular decode: block (bi, bj) with bi <= bj
    int bi = 0, rem = blockIdx.x;
    while (rem >= NT - bi) { rem -= NT - bi; ++bi; }
    int bj = bi + rem;
    int i0 = bi * BM;
    int j0 = bj * BM;

    if (tid < 128)      slabR[tid]       = labels[i0 + tid];
    else                slabC[tid - 128] = labels[j0 + tid - 128];

    const unsigned short* Ag = xnb + (size_t)i0 * DEMB;
    const unsigned short* Bg = xnb + (size_t)j0 * DEMB;

    int c0 = (kgrp * 16) ^ sw;
    int c1 = (64 + kgrp * 16) ^ sw;
    int abase = (wr * 64 + arow) * 128;
    int bbase = (wc * 64 + arow) * 128;

    f32x4 acc[4][4] = {};

    auto stage = [&](int buf, int k0) {
#pragma unroll
        for (int i = 0; i < 4; ++i) {
            int idx  = i * 256 + tid;
            int row  = idx >> 3;
            int colb = (idx & 7) << 4;
            int scol = (colb ^ ((row & 7) << 4)) >> 1;
            const unsigned short* sa = Ag + (size_t)row * DEMB + k0 + scol;
            const unsigned short* sb = Bg + (size_t)row * DEMB + k0 + scol;
            unsigned short* da = tile + buf * 8192 + i * 2048 + wid * 512;
            unsigned short* db = tile + 16384 + buf * 8192 + i * 2048 + wid * 512;
            gload16(sa, da);
            gload16(sb, db);
        }
    };

    stage(0, 0);
#pragma unroll
    for (int ks = 0; ks < 4; ++ks) {
        __syncthreads();
        if (ks < 3) stage((ks + 1) & 1, (ks + 1) * BK);
        const char* At = (const char*)(tile + (ks & 1) * 8192);
        const char* Bt = (const char*)(tile + 16384 + (ks & 1) * 8192);
        bf16x8 a[4][2], b[4][2];
#pragma unroll
        for (int m = 0; m < 4; ++m) {
            a[m][0] = *(const bf16x8*)(At + abase + m * 2048 + c0);
            a[m][1] = *(const bf16x8*)(At + abase + m * 2048 + c1);
            b[m][0] = *(const bf16x8*)(Bt + bbase + m * 2048 + c0);
            b[m][1] = *(const bf16x8*)(Bt + bbase + m * 2048 + c1);
        }
#pragma unroll
        for (int m = 0; m < 4; ++m)
#pragma unroll
            for (int n = 0; n < 4; ++n) {
                acc[m][n] = __builtin_amdgcn_mfma_f32_16x16x32_bf16(a[m][0], b[n][0], acc[m][n], 0, 0, 0);
                acc[m][n] = __builtin_amdgcn_mfma_f32_16x16x32_bf16(a[m][1], b[n][1], acc[m][n], 0, 0, 0);
            }
    }

    __syncthreads();                              // tile reads done; reuse LDS
    float* smaxr = (float*)tile;                  // [2][128]
    float* smaxc = (float*)tile + 256;            // [2][128]

    int cl[4];
#pragma unroll
    for (int n = 0; n < 4; ++n) cl[n] = slabC[wc * 64 + n * 16 + arow];

    float cmx[4] = {-1e30f, -1e30f, -1e30f, -1e30f};
#pragma unroll
    for (int m = 0; m < 4; ++m) {
#pragma unroll
        for (int r = 0; r < 4; ++r) {
            int rl = slabR[wr * 64 + m * 16 + kgrp * 4 + r];
            float v = -1e30f;
#pragma unroll
            for (int n = 0; n < 4; ++n) {
                float av = acc[m][n][r];
                if (cl[n] != rl) {
                    v = fmaxf(v, av);
                    cmx[n] = fmaxf(cmx[n], av);
                }
            }
#pragma unroll
            for (int msk = 1; msk < 16; msk <<= 1) v = fmaxf(v, __shfl_xor(v, msk));
            if (arow == 0) smaxr[wc * 128 + wr * 64 + m * 16 + kgrp * 4 + r] = v;
        }
    }
#pragma unroll
    for (int n = 0; n < 4; ++n) {
        float w = cmx[n];
        w = fmaxf(w, __shfl_xor(w, 16));
        w = fmaxf(w, __shfl_xor(w, 32));
        if (kgrp == 0) smaxc[wr * 128 + wc * 64 + n * 16 + arow] = w;
    }
    __syncthreads();
    if (tid < 128) {
        float v = fmaxf(smaxr[tid], smaxr[128 + tid]);
        if (v > -1e29f) atomicMax(amax + i0 + tid, encf(v));
    } else {
        int t = tid - 128;
        float v = fmaxf(smaxc[t], smaxc[128 + t]);
        if (v > -1e29f) atomicMax(amax + j0 + t, encf(v));
    }
}

// K3: per-class pair losses. One block per class.
// Phase 1: ordered class row-list via ballot-rank scan (deterministic).
// Phase 2: gather class rows + dmin into LDS, build pair list.
// Phase 3: 16-lane groups compute pair dots (4 pairs in flight per wave).
__global__ __launch_bounds__(256) void k_cpairs(const unsigned short* __restrict__ xnb,
                                                const int* __restrict__ labels,
                                                const unsigned* __restrict__ amax,
                                                float* __restrict__ closs,
                                                int* __restrict__ ccnt) {
    extern __shared__ char lds2[];
    int* slab = (int*)lds2;                        // 32KB (phase 1)
    unsigned short* srows = (unsigned short*)lds2; // 48KB (phase 2+, overwrites slab)
    __shared__ int clist[NCAP];
    __shared__ float sdm[NCAP];
    __shared__ unsigned char shn[NCAP];
    __shared__ unsigned short pl[NCAP * (NCAP - 1) / 2];   // 4560 pairs
    __shared__ int wcnt[4], woff[4], snc;
    __shared__ float slloss[16];
    __shared__ int slcnt[16];

    int c   = blockIdx.x;
    int tid = threadIdx.x, wid = tid >> 6, lane = tid & 63;

    // phase 1a: labels -> LDS
    for (int i = tid; i < NROWS / 4; i += 256)
        ((int4*)slab)[i] = ((const int4*)labels)[i];
    __syncthreads();

    // phase 1b: count class members in this wave's window [wid*2048, +2048)
    int base = wid * 2048;
    int cnt = 0;
    for (int s = 0; s < 8; ++s) {
        int b0 = base + s * 256;
        cnt += __popcll(__ballot(slab[b0 + lane] == c));
        cnt += __popcll(__ballot(slab[b0 + 64 + lane] == c));
        cnt += __popcll(__ballot(slab[b0 + 128 + lane] == c));
        cnt += __popcll(__ballot(slab[b0 + 192 + lane] == c));
    }
    if (lane == 0) wcnt[wid] = cnt;
    __syncthreads();
    if (tid == 0) {
        int o = 0;
        for (int w = 0; w < 4; ++w) { woff[w] = o; o += wcnt[w]; }
        snc = (o > NCAP) ? NCAP : o;
    }
    __syncthreads();
    int nc = snc;

    // phase 1c: write ordered row indices
    int off = woff[wid];
    for (int s = 0; s < 8; ++s) {
        int b0 = base + s * 256;
#pragma unroll
        for (int e = 0; e < 4; ++e) {
            int idx = b0 + e * 64 + lane;
            int l = slab[idx];
            unsigned long long m = __ballot(l == c);
            int rank = __popcll(m & ((1ull << lane) - 1ull));
            if (l == c && off + rank < NCAP) clist[off + rank] = idx;
            off += __popcll(m);
        }
    }
    __syncthreads();   // clist ready; slab dead

    // phase 2: gather rows, dmin, pair list
    int nch = nc * 32;                 // 16B chunks (32 per 512B row)
    for (int ch = tid; ch < nch; ch += 256) {
        int r = ch >> 5, cc = ch & 31;
        *(bf16x8*)(srows + r * 256 + cc * 8) =
            *(const bf16x8*)(xnb + (size_t)clist[r] * DEMB + cc * 8);
    }
    if (tid < nc) {
        unsigned e = amax[clist[tid]];
        shn[tid] = (e != 0u);
        sdm[tid] = 1.0f - decf(e);
    }
    int npairs = nc * (nc - 1) / 2;
    for (int p = tid; p < npairs; p += 256) {
        int i = 0, rem = p;
        while (rem >= nc - 1 - i) { rem -= nc - 1 - i; ++i; }
        pl[p] = (unsigned short)((i << 8) | (i + 1 + rem));
    }
    __syncthreads();

    // phase 3: pair dots, 16-lane groups
    int slot = tid >> 4, gl = tid & 15;
    float gloss = 0.f;
    int gcnt = 0;
    for (int p = slot; p < npairs; p += 16) {
        int pr = pl[p], i = pr >> 8, j = pr & 255;
        bf16x8 a0 = *(const bf16x8*)(srows + i * 256 + gl * 16);
        bf16x8 a1 = *(const bf16x8*)(srows + i * 256 + gl * 16 + 8);
        bf16x8 b0 = *(const bf16x8*)(srows + j * 256 + gl * 16);
        bf16x8 b1 = *(const bf16x8*)(srows + j * 256 + gl * 16 + 8);
        float dot = 0.f;
#pragma unroll
        for (int e = 0; e < 8; ++e) {
            dot += b2f((unsigned short)a0[e]) * b2f((unsigned short)b0[e]);
            dot += b2f((unsigned short)a1[e]) * b2f((unsigned short)b1[e]);
        }
#pragma unroll
        for (int msk = 1; msk < 16; msk <<= 1) dot += __shfl_xor(dot, msk);
        if (gl == 0 && shn[i]) {
            gloss += fmaxf(1.0f - dot - sdm[i] + MARGIN, 0.0f);
            gcnt += 1;
        }
    }
    if (gl == 0) { slloss[slot] = gloss; slcnt[slot] = gcnt; }
    __syncthreads();
    if (tid == 0) {
        float s = 0.f; int k = 0;
        for (int q = 0; q < 16; ++q) { s += slloss[q]; k += slcnt[q]; }
        closs[c] = s; ccnt[c] = k;
    }
}

// K4: final reduce over 512 classes -> out[0]=loss, out[1]=count
__global__ __launch_bounds__(256) void k_final(const float* __restrict__ closs,
                                               const int* __restrict__ ccnt,
                                               float* __restrict__ out) {
    __shared__ float sl[256];
    __shared__ int   sc[256];
    int tid = threadIdx.x;
    float s = closs[tid] + closs[tid + 256];
    int   k = ccnt[tid] + ccnt[tid + 256];
    sl[tid] = s; sc[tid] = k;
    __syncthreads();
    for (int st = 128; st > 0; st >>= 1) {
        if (tid < st) {
            sl[tid] += sl[tid + st];
            sc[tid] += sc[tid + st];
        }
        __syncthreads();
    }
    if (tid == 0) {
        out[0] = (sc[0] > 0) ? sl[0] / (float)sc[0] : 0.0f;
        out[1] = (float)sc[0];
    }
}

extern "C" void kernel_launch(void* const* d_in, const int* in_sizes, int n_in,
                              void* d_out, int out_size, void* d_ws, size_t ws_size,
                              hipStream_t stream) {
    const float* emb  = (const float*)d_in[0];
    const int* labels = (const int*)d_in[1];
    float* out = (float*)d_out;

    char* ws = (char*)d_ws;
    unsigned short* xnb = (unsigned short*)ws;                           // 4 MB
    unsigned* amax = (unsigned*)(ws + (size_t)4 * 1024 * 1024);          // 32 KB
    float* closs   = (float*)   (ws + (size_t)4 * 1024 * 1024 + 32768);  // 2 KB
    int*   ccnt    = (int*)     (ws + (size_t)4 * 1024 * 1024 + 40960);  // 2 KB

    k_norm<<<NROWS / 4, 256, 0, stream>>>(emb, xnb);
    hipMemsetAsync(amax, 0, NROWS * sizeof(unsigned), stream);
    k_maxneg<<<NBLK, 256, 65536, stream>>>(xnb, labels, amax);
    k_cpairs<<<NCLS, 256, 49152, stream>>>(xnb, labels, amax, closs, ccnt);
    k_final<<<1, 256, 0, stream>>>(closs, ccnt, out);
}

// Round 4
// 81.773 us; speedup vs baseline: 3.4744x; 1.0796x over previous
//
#include <hip/hip_runtime.h>
#include <hip/hip_bf16.h>

#define NROWS 8192
#define DEMB 256
#define MARGIN 0.2f
#define NCLS 512
#define NCAP 96                  // max class size (mean 16; P(>96) ~ 0)
#define TPC 8                    // B tiles (128 cols) per chunk
#define NSTEP 16                 // 8 tiles * 2 half-K steps (BK=128)

typedef __attribute__((ext_vector_type(4))) float f32x4;
typedef __attribute__((ext_vector_type(8))) short bf16x8;

static __device__ __forceinline__ unsigned short f2b(float f) {
    unsigned u = __builtin_bit_cast(unsigned, f);
    u += 0x7fffu + ((u >> 16) & 1u);           // RNE round to bf16
    return (unsigned short)(u >> 16);
}
static __device__ __forceinline__ float b2f(unsigned short b) {
    unsigned u = ((unsigned)b) << 16;
    return __builtin_bit_cast(float, u);
}
// order-preserving f32 -> u32 encode (max-compatible; finite values never encode to 0)
static __device__ __forceinline__ unsigned encf(float f) {
    unsigned u = __builtin_bit_cast(unsigned, f);
    return (u & 0x80000000u) ? ~u : (u | 0x80000000u);
}
static __device__ __forceinline__ float decf(unsigned e) {
    unsigned u = (e & 0x80000000u) ? (e ^ 0x80000000u) : ~e;
    return __builtin_bit_cast(float, u);
}
static __device__ __forceinline__ void gload16(const void* g, void* l) {
    __builtin_amdgcn_global_load_lds(
        (const __attribute__((address_space(1))) unsigned int*)g,
        (__attribute__((address_space(3))) unsigned int*)l, 16, 0, 0);
}

// K1: row-L2-normalize fp32 -> bf16; also zero amax (replaces memset dispatch).
__global__ __launch_bounds__(256) void k_norm(const float* __restrict__ x,
                                              unsigned short* __restrict__ xnb,
                                              unsigned* __restrict__ amax) {
    int gid = blockIdx.x * blockDim.x + threadIdx.x;
    if (gid < NROWS) amax[gid] = 0u;
    int row  = gid >> 6;
    int lane = threadIdx.x & 63;
    const float4* p = reinterpret_cast<const float4*>(x + (size_t)row * DEMB) + lane;
    float4 v = *p;
    float s = v.x * v.x + v.y * v.y + v.z * v.z + v.w * v.w;
#pragma unroll
    for (int m = 1; m < 64; m <<= 1) s += __shfl_xor(s, m);
    float inv = 1.0f / fmaxf(sqrtf(s), 1e-8f);
    ushort4 o;
    o.x = f2b(v.x * inv); o.y = f2b(v.y * inv);
    o.z = f2b(v.z * inv); o.w = f2b(v.w * inv);
    *(reinterpret_cast<ushort4*>(xnb + (size_t)row * DEMB) + lane) = o;
}

// K2: strip-streaming MFMA row-max. Grid (64 strips, 8 chunks), 512 threads.
// A-strip fragments hoisted to registers (never re-read); B streamed through
// 16-step double-buffered LDS pipeline (BK=128, 32KB/step, XOR-swizzled).
// Row-max accumulated in registers; one atomicMax set per block at the end.
__global__ __launch_bounds__(512, 2) void k_maxneg(const unsigned short* __restrict__ xnb,
                                                   const int* __restrict__ labels,
                                                   unsigned* __restrict__ amax) {
    extern __shared__ char lds[];
    unsigned short* Bl = (unsigned short*)lds;   // dbuf: 2 x 32KB

    int tid  = threadIdx.x;
    int wid  = tid >> 6, lane = tid & 63;
    int wr   = wid >> 1, wc = wid & 1;           // 4 row-subwaves x 2 col-subwaves
    int arow = lane & 15, kgrp = lane >> 4;

    int i0 = blockIdx.x * 128;
    int j0 = blockIdx.y * (TPC * 128);

    // Hoist A fragments: row = i0 + wr*32 + m*16 + arow, k = kk*32 + kgrp*8
    bf16x8 a[2][8];
    const unsigned short* ap0 = xnb + (size_t)(i0 + wr * 32 + arow) * DEMB + kgrp * 8;
#pragma unroll
    for (int m = 0; m < 2; ++m)
#pragma unroll
        for (int kk = 0; kk < 8; ++kk)
            a[m][kk] = *(const bf16x8*)(ap0 + m * 16 * DEMB + kk * 32);

    int rlab[2][4];
#pragma unroll
    for (int m = 0; m < 2; ++m)
#pragma unroll
        for (int r = 0; r < 4; ++r)
            rlab[m][r] = labels[i0 + wr * 32 + m * 16 + kgrp * 4 + r];

    float rmax[2][4] = {{-1e30f, -1e30f, -1e30f, -1e30f},
                        {-1e30f, -1e30f, -1e30f, -1e30f}};
    f32x4 acc[2][4] = {};

    // stage B half-tile: tile t, k-half h -> 128 rows x 128 k-cols = 32KB
    auto stage = [&](int buf, int t, int h) {
#pragma unroll
        for (int is = 0; is < 4; ++is) {
            int idx  = is * 512 + tid;                  // 16B chunk id 0..2047
            int row  = idx >> 4;                        // 16 chunks per 256B row
            int colb = (idx & 15) << 4;
            int scol = (colb ^ ((row & 15) << 4)) >> 1; // pre-swizzled elem col
            const unsigned short* src =
                xnb + (size_t)(j0 + t * 128 + row) * DEMB + h * 128 + scol;
            unsigned short* dst = Bl + buf * 16384 + is * 4096 + wid * 512;
            gload16(src, dst);
        }
    };

    int clab[4], nlab[4];
    stage(0, 0, 0);
#pragma unroll
    for (int n = 0; n < 4; ++n) clab[n] = labels[j0 + wc * 64 + n * 16 + arow];

    int sw = arow << 4;
    for (int s = 0; s < NSTEP; ++s) {
        __syncthreads();                                 // buf[s&1] ready
        if (s + 1 < NSTEP) stage((s + 1) & 1, (s + 1) >> 1, (s + 1) & 1);
        int tile = s >> 1, h = s & 1;
        if (h == 0 && tile + 1 < TPC) {
#pragma unroll
            for (int n = 0; n < 4; ++n)
                nlab[n] = labels[j0 + (tile + 1) * 128 + wc * 64 + n * 16 + arow];
        }
        const char* Bt = (const char*)(Bl + (s & 1) * 16384);
        bf16x8 b[4][4];
#pragma unroll
        for (int n = 0; n < 4; ++n) {
            int rb = (wc * 64 + n * 16 + arow) * 256;
#pragma unroll
            for (int ksl = 0; ksl < 4; ++ksl)
                b[n][ksl] = *(const bf16x8*)(Bt + rb + ((ksl * 64 + kgrp * 16) ^ sw));
        }
#pragma unroll
        for (int m = 0; m < 2; ++m)
#pragma unroll
            for (int n = 0; n < 4; ++n)
#pragma unroll
                for (int ksl = 0; ksl < 4; ++ksl)
                    acc[m][n] = __builtin_amdgcn_mfma_f32_16x16x32_bf16(
                        a[m][h * 4 + ksl], b[n][ksl], acc[m][n], 0, 0, 0);
        if (h == 1) {                                    // tile done: masked fold
#pragma unroll
            for (int m = 0; m < 2; ++m)
#pragma unroll
                for (int r = 0; r < 4; ++r) {
                    float v = rmax[m][r];
                    int rl = rlab[m][r];
#pragma unroll
                    for (int n = 0; n < 4; ++n)
                        if (clab[n] != rl) v = fmaxf(v, acc[m][n][r]);
                    rmax[m][r] = v;
                }
#pragma unroll
            for (int m = 0; m < 2; ++m)
#pragma unroll
                for (int n = 0; n < 4; ++n) acc[m][n] = (f32x4){0.f, 0.f, 0.f, 0.f};
#pragma unroll
            for (int n = 0; n < 4; ++n) clab[n] = nlab[n];
        }
    }

    // Reduce over 16 col-lanes, combine wc pair via LDS, one atomic per row.
    float* smax = (float*)Bl;                            // [2][128] in buf0 (dead)
#pragma unroll
    for (int m = 0; m < 2; ++m)
#pragma unroll
        for (int r = 0; r < 4; ++r) {
            float v = rmax[m][r];
#pragma unroll
            for (int msk = 1; msk < 16; msk <<= 1) v = fmaxf(v, __shfl_xor(v, msk));
            if (arow == 0) smax[wc * 128 + wr * 32 + m * 16 + kgrp * 4 + r] = v;
        }
    __syncthreads();
    if (tid < 128) {
        float v = fmaxf(smax[tid], smax[128 + tid]);
        if (v > -1e29f) atomicMax(amax + i0 + tid, encf(v));
    }
}

// K3: per-class pair losses. One block per class; labels read straight from L2.
__global__ __launch_bounds__(256) void k_cpairs(const unsigned short* __restrict__ xnb,
                                                const int* __restrict__ labels,
                                                const unsigned* __restrict__ amax,
                                                float* __restrict__ closs,
                                                int* __restrict__ ccnt) {
    extern __shared__ char lds2[];
    unsigned short* srows = (unsigned short*)lds2;       // 48KB class rows
    __shared__ int clist[NCAP];
    __shared__ float sdm[NCAP];
    __shared__ unsigned char shn[NCAP];
    __shared__ unsigned short pl[NCAP * (NCAP - 1) / 2];
    __shared__ int wcnt[4], woff[4], snc;
    __shared__ float slloss[16];
    __shared__ int slcnt[16];

    int c   = blockIdx.x;
    int tid = threadIdx.x, wid = tid >> 6, lane = tid & 63;

    // phase 1a: per-wave member counts over window [wid*2048, +2048)
    int base = wid * 2048;
    int cnt = 0;
    for (int s = 0; s < 8; ++s) {
        int b0 = base + s * 256;
#pragma unroll
        for (int e = 0; e < 4; ++e)
            cnt += __popcll(__ballot(labels[b0 + e * 64 + lane] == c));
    }
    if (lane == 0) wcnt[wid] = cnt;
    __syncthreads();
    if (tid == 0) {
        int o = 0;
        for (int w = 0; w < 4; ++w) { woff[w] = o; o += wcnt[w]; }
        snc = (o > NCAP) ? NCAP : o;
    }
    __syncthreads();
    int nc = snc;

    // phase 1b: ordered row indices via ballot-rank
    int off = woff[wid];
    for (int s = 0; s < 8; ++s) {
        int b0 = base + s * 256;
#pragma unroll
        for (int e = 0; e < 4; ++e) {
            int idx = b0 + e * 64 + lane;
            bool hit = (labels[idx] == c);
            unsigned long long m = __ballot(hit);
            int rank = __popcll(m & ((1ull << lane) - 1ull));
            if (hit && off + rank < NCAP) clist[off + rank] = idx;
            off += __popcll(m);
        }
    }
    __syncthreads();

    // phase 2: gather rows, dmin, pair list
    int nch = nc * 32;
    for (int ch = tid; ch < nch; ch += 256) {
        int r = ch >> 5, cc = ch & 31;
        *(bf16x8*)(srows + r * 256 + cc * 8) =
            *(const bf16x8*)(xnb + (size_t)clist[r] * DEMB + cc * 8);
    }
    if (tid < nc) {
        unsigned e = amax[clist[tid]];
        shn[tid] = (e != 0u);
        sdm[tid] = 1.0f - decf(e);
    }
    int npairs = nc * (nc - 1) / 2;
    for (int p = tid; p < npairs; p += 256) {
        int i = 0, rem = p;
        while (rem >= nc - 1 - i) { rem -= nc - 1 - i; ++i; }
        pl[p] = (unsigned short)((i << 8) | (i + 1 + rem));
    }
    __syncthreads();

    // phase 3: pair dots, 16-lane groups
    int slot = tid >> 4, gl = tid & 15;
    float gloss = 0.f;
    int gcnt = 0;
    for (int p = slot; p < npairs; p += 16) {
        int pr = pl[p], i = pr >> 8, j = pr & 255;
        bf16x8 a0 = *(const bf16x8*)(srows + i * 256 + gl * 16);
        bf16x8 a1 = *(const bf16x8*)(srows + i * 256 + gl * 16 + 8);
        bf16x8 b0 = *(const bf16x8*)(srows + j * 256 + gl * 16);
        bf16x8 b1 = *(const bf16x8*)(srows + j * 256 + gl * 16 + 8);
        float dot = 0.f;
#pragma unroll
        for (int e = 0; e < 8; ++e) {
            dot += b2f((unsigned short)a0[e]) * b2f((unsigned short)b0[e]);
            dot += b2f((unsigned short)a1[e]) * b2f((unsigned short)b1[e]);
        }
#pragma unroll
        for (int msk = 1; msk < 16; msk <<= 1) dot += __shfl_xor(dot, msk);
        if (gl == 0 && shn[i]) {
            gloss += fmaxf(1.0f - dot - sdm[i] + MARGIN, 0.0f);
            gcnt += 1;
        }
    }
    if (gl == 0) { slloss[slot] = gloss; slcnt[slot] = gcnt; }
    __syncthreads();
    if (tid == 0) {
        float s = 0.f; int k = 0;
        for (int q = 0; q < 16; ++q) { s += slloss[q]; k += slcnt[q]; }
        closs[c] = s; ccnt[c] = k;
    }
}

// K4: final reduce over 512 classes -> out[0]=loss, out[1]=count
__global__ __launch_bounds__(256) void k_final(const float* __restrict__ closs,
                                               const int* __restrict__ ccnt,
                                               float* __restrict__ out) {
    __shared__ float sl[256];
    __shared__ int   sc[256];
    int tid = threadIdx.x;
    float s = closs[tid] + closs[tid + 256];
    int   k = ccnt[tid] + ccnt[tid + 256];
    sl[tid] = s; sc[tid] = k;
    __syncthreads();
    for (int st = 128; st > 0; st >>= 1) {
        if (tid < st) {
            sl[tid] += sl[tid + st];
            sc[tid] += sc[tid + st];
        }
        __syncthreads();
    }
    if (tid == 0) {
        out[0] = (sc[0] > 0) ? sl[0] / (float)sc[0] : 0.0f;
        out[1] = (float)sc[0];
    }
}

extern "C" void kernel_launch(void* const* d_in, const int* in_sizes, int n_in,
                              void* d_out, int out_size, void* d_ws, size_t ws_size,
                              hipStream_t stream) {
    const float* emb  = (const float*)d_in[0];
    const int* labels = (const int*)d_in[1];
    float* out = (float*)d_out;

    char* ws = (char*)d_ws;
    unsigned short* xnb = (unsigned short*)ws;                           // 4 MB
    unsigned* amax = (unsigned*)(ws + (size_t)4 * 1024 * 1024);          // 32 KB
    float* closs   = (float*)   (ws + (size_t)4 * 1024 * 1024 + 32768);  // 2 KB
    int*   ccnt    = (int*)     (ws + (size_t)4 * 1024 * 1024 + 40960);  // 2 KB

    k_norm<<<NROWS / 4, 256, 0, stream>>>(emb, xnb, amax);
    dim3 g2(NROWS / 128, NCLS / 64);   // 64 strips x 8 chunks
    k_maxneg<<<g2, 512, 65536, stream>>>(xnb, labels, amax);
    k_cpairs<<<NCLS, 256, 49152, stream>>>(xnb, labels, amax, closs, ccnt);
    k_final<<<1, 256, 0, stream>>>(closs, ccnt, out);
}